// Round 1
// baseline (57868.988 us; speedup 1.0000x reference)
//
#include <hip/hip_runtime.h>
#include <hip/hip_bf16.h>
#include <math.h>

#define S_LEN  1024
#define DMODEL 5120
#define QLORA  1536
#define KVLORA 512
#define ROPE_D 64
#define NOPE_D 128
#define VDIM_D 128
#define QHEAD  192
#define NHEAD  128

typedef __hip_bfloat16 bf16;

__device__ __forceinline__ float toF(float x) { return x; }
__device__ __forceinline__ float toF(bf16 x)  { return __bfloat162float(x); }

// ---------------------------------------------------------------------------
// Generic tiled GEMM: C(MxN) = A(MxK) @ B(KxN), row-major, fp32 accumulate.
// MODE 0: fp32 C;  MODE 1: bf16 C;  MODE 2: bf16 C written to (H, S, 192)
// head-major layout (n -> h = n/192, j = n%192; addr = ((h*S)+m)*192+j).
// Dims must be multiples of the tile (all shapes here are).
// ---------------------------------------------------------------------------
template<typename TA, int MODE>
__global__ __launch_bounds__(256) void gemm64(const TA* __restrict__ A,
                                              const float* __restrict__ B,
                                              void* __restrict__ Cout,
                                              int M, int N, int K) {
  __shared__ float As[16][64];
  __shared__ float Bs[16][65];
  const int n0 = blockIdx.x * 64, m0 = blockIdx.y * 64;
  const int tid = threadIdx.x;
  const int tn = tid & 15, tm = tid >> 4;
  float acc[4][4];
#pragma unroll
  for (int x = 0; x < 4; ++x)
#pragma unroll
    for (int y = 0; y < 4; ++y) acc[x][y] = 0.f;

  const int ar = tid >> 2, ac0 = (tid & 3) * 4;  // A tile: 64 rows x 16 cols
  const int br = tid >> 6, bc = tid & 63;        // B tile: 16 rows x 64 cols

  for (int kk = 0; kk < K; kk += 16) {
    const TA* Ap = A + (size_t)(m0 + ar) * K + kk + ac0;
#pragma unroll
    for (int i = 0; i < 4; ++i) As[ac0 + i][ar] = toF(Ap[i]);
    const float* Bp = B + (size_t)(kk + br) * N + n0 + bc;
#pragma unroll
    for (int i = 0; i < 4; ++i) Bs[br + 4 * i][bc] = Bp[(size_t)(4 * i) * N];
    __syncthreads();
#pragma unroll
    for (int k = 0; k < 16; ++k) {
      float a[4], b[4];
#pragma unroll
      for (int x = 0; x < 4; ++x) a[x] = As[k][tm * 4 + x];
#pragma unroll
      for (int y = 0; y < 4; ++y) b[y] = Bs[k][tn * 4 + y];
#pragma unroll
      for (int x = 0; x < 4; ++x)
#pragma unroll
        for (int y = 0; y < 4; ++y) acc[x][y] += a[x] * b[y];
    }
    __syncthreads();
  }

#pragma unroll
  for (int x = 0; x < 4; ++x) {
    const int m = m0 + tm * 4 + x;
#pragma unroll
    for (int y = 0; y < 4; ++y) {
      const int n = n0 + tn * 4 + y;
      if (MODE == 0) {
        ((float*)Cout)[(size_t)m * N + n] = acc[x][y];
      } else if (MODE == 1) {
        ((bf16*)Cout)[(size_t)m * N + n] = __float2bfloat16(acc[x][y]);
      } else {
        const int h = n / QHEAD, j = n - h * QHEAD;
        ((bf16*)Cout)[((size_t)h * S_LEN + m) * QHEAD + j] = __float2bfloat16(acc[x][y]);
      }
    }
  }
}

// ---------------------------------------------------------------------------
// RMSNorm over rows of length N (bf16 in, bf16 out), fp32 math.
// ---------------------------------------------------------------------------
__global__ __launch_bounds__(256) void rmsnorm_kernel(const bf16* __restrict__ in,
                                                      const float* __restrict__ w,
                                                      bf16* __restrict__ out, int N) {
  const int row = blockIdx.x, tid = threadIdx.x;
  __shared__ float red[256];
  float ss = 0.f;
  for (int c = tid; c < N; c += 256) { float x = toF(in[(size_t)row * N + c]); ss += x * x; }
  red[tid] = ss; __syncthreads();
  for (int s = 128; s > 0; s >>= 1) { if (tid < s) red[tid] += red[tid + s]; __syncthreads(); }
  const float rs = rsqrtf(red[0] / (float)N + 1e-6f);
  for (int c = tid; c < N; c += 256) {
    float x = toF(in[(size_t)row * N + c]);
    out[(size_t)row * N + c] = __float2bfloat16(x * rs * w[c]);
  }
}

// ---------------------------------------------------------------------------
// Build k_full (S x 576 bf16): cols 0..511 = rmsnorm(kv[:, :512]) (latent),
// cols 512..575 = rope(kv[:, 512:576]). One block per sequence row.
// ---------------------------------------------------------------------------
__global__ __launch_bounds__(256) void kfull_kernel(const float* __restrict__ kv,
                                                    const float* __restrict__ w,
                                                    const float* __restrict__ cosb,
                                                    const float* __restrict__ sinb,
                                                    bf16* __restrict__ kfull) {
  const int s = blockIdx.x, tid = threadIdx.x;
  __shared__ float red[256];
  const float* row = kv + (size_t)s * 576;
  const float x0 = row[tid], x1 = row[256 + tid];
  red[tid] = x0 * x0 + x1 * x1; __syncthreads();
  for (int t = 128; t > 0; t >>= 1) { if (tid < t) red[tid] += red[tid + t]; __syncthreads(); }
  const float rs = rsqrtf(red[0] / 512.f + 1e-6f);
  bf16* krow = kfull + (size_t)s * 576;
  krow[tid]       = __float2bfloat16(x0 * rs * w[tid]);
  krow[256 + tid] = __float2bfloat16(x1 * rs * w[256 + tid]);
  if (tid < 32) {
    const int j = tid;
    const float a = row[512 + j], b = row[544 + j];
    const float* cs = cosb + (size_t)s * 64;
    const float* sn = sinb + (size_t)s * 64;
    krow[512 + j] = __float2bfloat16(a * cs[j] - b * sn[j]);          // j < 32: x*cos - x[j+32]*sin
    krow[544 + j] = __float2bfloat16(b * cs[32 + j] + a * sn[32 + j]); // j>=32: x*cos + x[j-32]*sin
  }
}

// ---------------------------------------------------------------------------
// RoPE on q_pe in-place in q_perm (H, S, 192) layout; one thread owns the
// (j, j+32) pair so the in-place update has no race.
// ---------------------------------------------------------------------------
__global__ __launch_bounds__(256) void rope_q_kernel(bf16* __restrict__ qperm,
                                                     const float* __restrict__ cosb,
                                                     const float* __restrict__ sinb) {
  const int idx = blockIdx.x * 256 + threadIdx.x;   // H*S*32 total
  const int h = idx >> 15;
  const int rem = idx & 32767;
  const int s = rem >> 5;
  const int j = rem & 31;
  bf16* base = qperm + ((size_t)h * S_LEN + s) * QHEAD + NOPE_D;
  const float a = toF(base[j]), b = toF(base[32 + j]);
  const float* cs = cosb + (size_t)s * 64;
  const float* sn = sinb + (size_t)s * 64;
  base[j]      = __float2bfloat16(a * cs[j] - b * sn[j]);
  base[32 + j] = __float2bfloat16(b * cs[32 + j] + a * sn[32 + j]);
}

// ---------------------------------------------------------------------------
// Fused MLA attention. Block = (head h, 16-row q tile). Fuses:
//   q_abs = q_nope_tile @ kc_w[h]  (16x512)   -> Qf LDS (with roped q_pe)
//   flash loop over 32-wide K tiles: S = Qf @ k_full^T * scale, causal,
//   online softmax, O += P @ latent  (O = 16x512 fp32 in LDS)
//   attn_v tile = (O / l) @ vc_w[h]  (16x128) -> global bf16
// LDS: 18KB Qf + 32KB O + 2KB S + 4KB qstage + rows = 57.5KB (<64KB).
// ---------------------------------------------------------------------------
#define BQ 16
__global__ __launch_bounds__(256) void attn_kernel(const bf16* __restrict__ qperm,
                                                   const bf16* __restrict__ kfull,
                                                   const float* __restrict__ kcw,
                                                   const float* __restrict__ vcw,
                                                   bf16* __restrict__ attnv,
                                                   float scale) {
  const int h = blockIdx.y, qb = blockIdx.x, r0 = qb * BQ, tid = threadIdx.x;
  __shared__ bf16  Qf[BQ][576];
  __shared__ float Ot[BQ][512];
  __shared__ float St[BQ][32];
  __shared__ float mrow[BQ], lrow[BQ], arow[BQ];
  __shared__ bf16  qstage[BQ][128];

  // stage q_nope tile + q_pe (already roped) into LDS
  for (int e = tid; e < BQ * 128; e += 256) {
    const int i = e >> 7, d = e & 127;
    qstage[i][d] = qperm[((size_t)h * S_LEN + r0 + i) * QHEAD + d];
  }
  for (int e = tid; e < BQ * 64; e += 256) {
    const int i = e >> 6, j = e & 63;
    Qf[i][512 + j] = qperm[((size_t)h * S_LEN + r0 + i) * QHEAD + NOPE_D + j];
  }
  __syncthreads();

  // q_abs = qstage (16x128) @ kc_w[h] (128x512)
  for (int e = tid; e < BQ * 512; e += 256) {
    const int i = e >> 9, l = e & 511;
    const float* kc = kcw + (size_t)h * 128 * 512 + l;
    float s = 0.f;
    for (int d = 0; d < 128; ++d) s += toF(qstage[i][d]) * kc[(size_t)d * 512];
    Qf[i][l] = __float2bfloat16(s);
  }
  for (int e = tid; e < BQ * 512; e += 256) Ot[e >> 9][e & 511] = 0.f;
  if (tid < BQ) { mrow[tid] = -INFINITY; lrow[tid] = 0.f; }
  __syncthreads();

  for (int k0 = 0; k0 < r0 + BQ; k0 += 32) {
    // scores tile (16x32)
    for (int e = tid; e < BQ * 32; e += 256) {
      const int i = e >> 5, j = e & 31;
      const int kk = k0 + j;
      float s;
      if (kk > r0 + i) {
        s = -INFINITY;                       // causal (also covers kk >= S)
      } else {
        s = 0.f;
        const bf16* krow = kfull + (size_t)kk * 576;
        for (int d = 0; d < 576; ++d) s += toF(Qf[i][d]) * toF(krow[d]);
        s *= scale;
      }
      St[i][j] = s;
    }
    __syncthreads();
    // online softmax per row (first tile always has a valid col -> mx finite)
    if (tid < BQ) {
      const int i = tid;
      float mx = mrow[i];
      for (int j = 0; j < 32; ++j) mx = fmaxf(mx, St[i][j]);
      const float alpha = expf(mrow[i] - mx);   // expf(-inf)=0 on first tile
      float sum = 0.f;
      for (int j = 0; j < 32; ++j) { const float p = expf(St[i][j] - mx); St[i][j] = p; sum += p; }
      lrow[i] = lrow[i] * alpha + sum;
      mrow[i] = mx; arow[i] = alpha;
    }
    __syncthreads();
    // O = O*alpha + P @ latent   (latent = k_full cols 0..511)
    const int jmax = min(32, S_LEN - k0);       // no OOB reads past S
    for (int e = tid; e < BQ * 512; e += 256) {
      const int i = e >> 9, v = e & 511;
      float o = Ot[i][v] * arow[i];
      const bf16* lat = kfull + (size_t)k0 * 576 + v;
      for (int j = 0; j < jmax; ++j) o += St[i][j] * toF(lat[(size_t)j * 576]);
      Ot[i][v] = o;
    }
    __syncthreads();
  }

  // normalize
  for (int e = tid; e < BQ * 512; e += 256) Ot[e >> 9][e & 511] /= lrow[e >> 9];
  __syncthreads();

  // attn_v tile = O (16x512) @ vc_w[h] (512x128)
  for (int e = tid; e < BQ * 128; e += 256) {
    const int i = e >> 7, c = e & 127;
    const float* vc = vcw + (size_t)h * 512 * 128 + c;
    float s = 0.f;
    for (int v = 0; v < 512; ++v) s += Ot[i][v] * vc[(size_t)v * 128];
    attnv[(size_t)(r0 + i) * (NHEAD * VDIM_D) + h * VDIM_D + c] = __float2bfloat16(s);
  }
}

// ---------------------------------------------------------------------------
extern "C" void kernel_launch(void* const* d_in, const int* in_sizes, int n_in,
                              void* d_out, int out_size, void* d_ws, size_t ws_size,
                              hipStream_t stream) {
  const float* hidden    = (const float*)d_in[0];
  const float* cosb      = (const float*)d_in[1];
  const float* sinb      = (const float*)d_in[2];
  const float* q_a_w     = (const float*)d_in[3];
  const float* q_a_ln_w  = (const float*)d_in[4];
  const float* q_b_w     = (const float*)d_in[5];
  const float* kv_a_w    = (const float*)d_in[6];
  const float* kv_a_ln_w = (const float*)d_in[7];
  const float* kc_w      = (const float*)d_in[8];
  const float* vc_w      = (const float*)d_in[9];
  const float* o_w       = (const float*)d_in[10];
  float* out = (float*)d_out;

  // workspace layout (bytes), total ~94 MB
  char* ws = (char*)d_ws;
  bf16*  qa    = (bf16*)(ws + 0);          // 1024x1536 bf16   (3.0 MB)
  bf16*  qan   = (bf16*)(ws + 3145728);    // 1024x1536 bf16   (3.0 MB)
  bf16*  qperm = (bf16*)(ws + 6291456);    // (H,S,192) bf16   (48 MB)
  float* kv    = (float*)(ws + 56623104);  // 1024x576 f32     (2.25 MB)
  bf16*  kfull = (bf16*)(ws + 58982400);   // 1024x576 bf16    (1.13 MB)
  bf16*  attnv = (bf16*)(ws + 60162048);   // 1024x16384 bf16  (32 MB)

  const double msc = 0.1 * log(40.0) + 1.0;
  const float scale = (float)(pow((double)QHEAD, -0.5) * msc * msc);

  // q_a: (1024x5120)@(5120x1536) -> qa
  gemm64<float, 1><<<dim3(QLORA / 64, S_LEN / 64), 256, 0, stream>>>(
      hidden, q_a_w, qa, S_LEN, QLORA, DMODEL);
  // rmsnorm(qa)
  rmsnorm_kernel<<<S_LEN, 256, 0, stream>>>(qa, q_a_ln_w, qan, QLORA);
  // q_b: (1024x1536)@(1536x24576) -> qperm (head-major)
  gemm64<bf16, 2><<<dim3((NHEAD * QHEAD) / 64, S_LEN / 64), 256, 0, stream>>>(
      qan, q_b_w, qperm, S_LEN, NHEAD * QHEAD, QLORA);
  // kv_a: (1024x5120)@(5120x576) -> kv
  gemm64<float, 0><<<dim3(576 / 64, S_LEN / 64), 256, 0, stream>>>(
      hidden, kv_a_w, kv, S_LEN, KVLORA + ROPE_D, DMODEL);
  // k_full = [rmsnorm(latent) | rope(k_pe)]
  kfull_kernel<<<S_LEN, 256, 0, stream>>>(kv, kv_a_ln_w, cosb, sinb, kfull);
  // rope q_pe in place
  rope_q_kernel<<<(NHEAD * S_LEN * 32) / 256, 256, 0, stream>>>(qperm, cosb, sinb);
  // fused attention (q absorb + flash + vc projection)
  attn_kernel<<<dim3(S_LEN / BQ, NHEAD), 256, 0, stream>>>(
      qperm, kfull, kc_w, vc_w, attnv, scale);
  // output projection: (1024x16384)@(16384x5120) -> out
  gemm64<bf16, 0><<<dim3(DMODEL / 64, S_LEN / 64), 256, 0, stream>>>(
      attnv, o_w, out, S_LEN, DMODEL, NHEAD * VDIM_D);
}